// Round 1
// baseline (6199.902 us; speedup 1.0000x reference)
//
#include <hip/hip_runtime.h>
#include <hip/hip_bf16.h>

// Problem constants
#define NROWS 16384
#define CDIM  512
#define KNB   10
#define TAU_INV 20.0f

// topk kernel tiling
constexpr int TX   = 32;    // x rows per block
constexpr int TYC  = 256;   // y cols per tile
constexpr int KC   = 32;    // k chunk staged in LDS
constexpr int PADK = 36;    // LDS row stride (floats) for xs/ys (16B-aligned, breaks pow2)
constexpr int SIMPAD = 260; // LDS row stride for sim tile (4r+s conflict-free scan)

// ---------------- kernel 1: inverse L2 norms ----------------
__global__ __launch_bounds__(64) void norms_kernel(const float* __restrict__ X,
                                                   const float* __restrict__ Y,
                                                   float* __restrict__ inv) {
    int b = blockIdx.x;
    const float* src = (b < NROWS) ? X : Y;
    int row = (b < NROWS) ? b : b - NROWS;
    const float4* p = reinterpret_cast<const float4*>(src + (size_t)row * CDIM);
    int t = threadIdx.x; // 64 threads = 1 wave
    float ss = 0.f;
    #pragma unroll
    for (int i = 0; i < CDIM / 4 / 64; ++i) {
        float4 v = p[t + i * 64];
        ss += v.x * v.x + v.y * v.y + v.z * v.z + v.w * v.w;
    }
    #pragma unroll
    for (int off = 32; off; off >>= 1) ss += __shfl_xor(ss, off, 64);
    if (t == 0) inv[b] = 1.0f / fmaxf(sqrtf(ss), 1e-12f);
}

// stable top-k comparator: matches jax.lax.top_k (desc values, asc index on ties)
__device__ __forceinline__ bool better(float v1, int i1, float v2, int i2) {
    return (v1 > v2) || (v1 == v2 && i1 < i2);
}

// ---------------- kernel 2: sim + streaming top-10 + softmax ----------------
__global__ __launch_bounds__(256, 2) void topk_kernel(const float* __restrict__ X,
                                                      const float* __restrict__ Y,
                                                      const float* __restrict__ invx,
                                                      const float* __restrict__ invy,
                                                      float* __restrict__ out) {
    __shared__ float xs[TX][PADK];       // 4608 B
    __shared__ float smem[TYC * PADK];   // 36864 B; reused as sim[32][260] and cand buffers

    const int t = threadIdx.x;
    const int rowBase = blockIdx.x * TX;
    const int ty = t >> 5, tx = t & 31;  // GEMM mapping: rows ty*4..+3, cols tx+32n
    const int rs = t >> 3, sl = t & 7;   // scan mapping: row rs, slot sl

    // register-resident running top-10 for row (rowBase+rs), columns sl+8k pattern
    float tv[KNB];
    int   tix[KNB];
    #pragma unroll
    for (int j = 0; j < KNB; ++j) { tv[j] = -1e30f; tix[j] = 0x7fffffff; }

    const float4* X4 = reinterpret_cast<const float4*>(X);
    const float4* Y4 = reinterpret_cast<const float4*>(Y);

    for (int tile = 0; tile < NROWS / TYC; ++tile) {
        const int colBase = tile * TYC;
        float acc[4][8];
        #pragma unroll
        for (int m = 0; m < 4; ++m)
            #pragma unroll
            for (int n = 0; n < 8; ++n) acc[m][n] = 0.f;

        for (int kc = 0; kc < CDIM / KC; ++kc) {
            const int kq = kc * (KC / 4); // float4 offset within row
            __syncthreads(); // previous use of smem (ys or sim scan) done

            // stage x chunk: 32 rows x 32 floats, one float4/thread
            {
                int lrow = t >> 3, lq = t & 7;
                float s = invx[rowBase + lrow];
                float4 v = X4[(size_t)(rowBase + lrow) * (CDIM / 4) + kq + lq];
                float4* dst = reinterpret_cast<float4*>(&xs[lrow][lq * 4]);
                *dst = make_float4(v.x * s, v.y * s, v.z * s, v.w * s);
            }
            // stage y chunk: 256 rows x 32 floats, 8 float4/thread
            #pragma unroll
            for (int it = 0; it < 8; ++it) {
                int l = t + 256 * it;
                int lrow = l >> 3, lq = l & 7;
                float s = invy[colBase + lrow];
                float4 v = Y4[(size_t)(colBase + lrow) * (CDIM / 4) + kq + lq];
                float4* dst = reinterpret_cast<float4*>(&smem[lrow * PADK + lq * 4]);
                *dst = make_float4(v.x * s, v.y * s, v.z * s, v.w * s);
            }
            __syncthreads();

            #pragma unroll
            for (int k = 0; k < KC; ++k) {
                float a0 = xs[ty * 4 + 0][k];
                float a1 = xs[ty * 4 + 1][k];
                float a2 = xs[ty * 4 + 2][k];
                float a3 = xs[ty * 4 + 3][k];
                #pragma unroll
                for (int n = 0; n < 8; ++n) {
                    float b = smem[(tx + 32 * n) * PADK + k];
                    acc[0][n] = fmaf(a0, b, acc[0][n]);
                    acc[1][n] = fmaf(a1, b, acc[1][n]);
                    acc[2][n] = fmaf(a2, b, acc[2][n]);
                    acc[3][n] = fmaf(a3, b, acc[3][n]);
                }
            }
        }

        // dump C tile to LDS (reuse ys region as sim[32][SIMPAD])
        __syncthreads(); // all waves done reading ys
        float* sim = smem;
        #pragma unroll
        for (int m = 0; m < 4; ++m)
            #pragma unroll
            for (int n = 0; n < 8; ++n)
                sim[(ty * 4 + m) * SIMPAD + tx + 32 * n] = acc[m][n];
        __syncthreads();

        // scan: 8 threads per row, thread sl covers cols sl+8k
        #pragma unroll
        for (int k = 0; k < TYC / 8; ++k) {
            float v = sim[rs * SIMPAD + sl + 8 * k];
            int col = colBase + sl + 8 * k;
            if (better(v, col, tv[KNB - 1], tix[KNB - 1])) {
                tv[KNB - 1] = v; tix[KNB - 1] = col;
                #pragma unroll
                for (int j = KNB - 1; j > 0; --j) {
                    if (better(tv[j], tix[j], tv[j - 1], tix[j - 1])) {
                        float fv = tv[j]; tv[j] = tv[j - 1]; tv[j - 1] = fv;
                        int fi = tix[j]; tix[j] = tix[j - 1]; tix[j - 1] = fi;
                    }
                }
            }
        }
        // loop top's __syncthreads() protects sim before next ys staging
    }

    // -------- final merge: 8 candidate lists -> top-10 per row --------
    __syncthreads();
    float* cv = smem;                               // [32][80] floats
    int*   ci = reinterpret_cast<int*>(smem + TX * 80); // [32][80] ints
    #pragma unroll
    for (int j = 0; j < KNB; ++j) {
        cv[rs * 80 + sl * KNB + j] = tv[j];
        ci[rs * 80 + sl * KNB + j] = tix[j];
    }
    __syncthreads();

    if (t < TX) {
        float mv[KNB]; int mi[KNB];
        #pragma unroll
        for (int j = 0; j < KNB; ++j) { mv[j] = -1e30f; mi[j] = 0x7fffffff; }
        for (int c = 0; c < 80; ++c) {
            float v = cv[t * 80 + c];
            int   id = ci[t * 80 + c];
            if (better(v, id, mv[KNB - 1], mi[KNB - 1])) {
                mv[KNB - 1] = v; mi[KNB - 1] = id;
                #pragma unroll
                for (int j = KNB - 1; j > 0; --j) {
                    if (better(mv[j], mi[j], mv[j - 1], mi[j - 1])) {
                        float fv = mv[j]; mv[j] = mv[j - 1]; mv[j - 1] = fv;
                        int fi = mi[j]; mi[j] = mi[j - 1]; mi[j - 1] = fi;
                    }
                }
            }
        }
        // softmax over mv/tau (shift by max = mv[0], list is sorted desc)
        float mmax = mv[0];
        float e[KNB]; float sum = 0.f;
        #pragma unroll
        for (int j = 0; j < KNB; ++j) { e[j] = __expf((mv[j] - mmax) * TAU_INV); sum += e[j]; }
        // recompute with precise expf for accuracy (avoid __expf fast-math drift)
        sum = 0.f;
        #pragma unroll
        for (int j = 0; j < KNB; ++j) { e[j] = expf((mv[j] - mmax) * TAU_INV); sum += e[j]; }

        const size_t gr = (size_t)rowBase + t;
        #pragma unroll
        for (int j = 0; j < KNB; ++j) {
            out[gr * KNB + j] = e[j] / sum;                                  // values
            out[(size_t)NROWS * KNB + gr * KNB + j] = (float)gr;             // indices[0] (rows)
            out[(size_t)2 * NROWS * KNB + gr * KNB + j] = (float)mi[j];      // indices[1] (cols)
        }
    }
}

extern "C" void kernel_launch(void* const* d_in, const int* in_sizes, int n_in,
                              void* d_out, int out_size, void* d_ws, size_t ws_size,
                              hipStream_t stream) {
    const float* X = (const float*)d_in[0];
    const float* Y = (const float*)d_in[1];
    float* inv = (float*)d_ws;              // [0,16384): invx, [16384,32768): invy
    float* out = (float*)d_out;

    norms_kernel<<<2 * NROWS, 64, 0, stream>>>(X, Y, inv);
    topk_kernel<<<NROWS / TX, 256, 0, stream>>>(X, Y, inv, inv + NROWS, out);
}